// Round 5
// baseline (111.206 us; speedup 1.0000x reference)
//
#include <hip/hip_runtime.h>
#include <math.h>

#define N_CLASSES 1000
#define FEAT_DIM 1024
#define PROJ_DIM 256
#define BATCH 32
#define NUM_SUPPORT 8192

// prelude grid layout
#define PW_BLOCKS 16   // prep_w: 64-k tile each
#define PX_BLOCKS 256  // proj_x (32 b x 8 cc)

typedef __attribute__((ext_vector_type(8))) _Float16 f16x8;
typedef __attribute__((ext_vector_type(2))) _Float16 f16x2;
typedef __attribute__((ext_vector_type(4))) float f32x4;

// ---------------------------------------------------------------------------
// Prelude (one dispatch): prep_w (W->fp16 n-major) | proj_x (xqh2=fp16(2xW)).
// Branch is uniform per block. (round-4 version, best measured)
// ---------------------------------------------------------------------------
__global__ __launch_bounds__(256) void prelude_kernel(
    const float* __restrict__ W, const float* __restrict__ x,
    _Float16* __restrict__ W1, _Float16* __restrict__ xqh2) {
  __shared__ float part[256];
  __shared__ _Float16 Lw[256][66];  // transpose tile, padded
  const int bid = blockIdx.x;
  const int t = threadIdx.x;

  if (bid < PW_BLOCKS) {
    // ---- prep_w: W (k-major) -> W1 (n-major fp16) via LDS transpose.
    const int k0 = bid * 64;
#pragma unroll 8
    for (int kk = 0; kk < 64; kk++) {
      Lw[t][kk] = (_Float16)W[(size_t)(k0 + kk) * PROJ_DIM + t];
    }
    __syncthreads();
#pragma unroll
    for (int i = 0; i < 8; i++) {
      *(f16x8*)&W1[(size_t)t * FEAT_DIM + k0 + i * 8] = *(f16x8*)&Lw[t][i * 8];
    }
  } else {
    // ---- proj_x: xqh2[b][col] = fp16(2 * (x@W)[b][col]); 4 independent
    // accumulators break the serial fmaf dependency chain.
    const int pxb = bid - PW_BLOCKS;
    const int b = pxb >> 3, cc = pxb & 7;
    const int col = t & 31, ks = t >> 5;
    const int gc = cc * 32 + col;
    const int k0 = ks * 128;
    float s0 = 0.f, s1 = 0.f, s2 = 0.f, s3 = 0.f;
#pragma unroll 8
    for (int k = 0; k < 128; k += 4) {
      s0 = fmaf(x[(size_t)b * FEAT_DIM + k0 + k],
                W[(size_t)(k0 + k) * PROJ_DIM + gc], s0);
      s1 = fmaf(x[(size_t)b * FEAT_DIM + k0 + k + 1],
                W[(size_t)(k0 + k + 1) * PROJ_DIM + gc], s1);
      s2 = fmaf(x[(size_t)b * FEAT_DIM + k0 + k + 2],
                W[(size_t)(k0 + k + 2) * PROJ_DIM + gc], s2);
      s3 = fmaf(x[(size_t)b * FEAT_DIM + k0 + k + 3],
                W[(size_t)(k0 + k + 3) * PROJ_DIM + gc], s3);
    }
    part[t] = (s0 + s1) + (s2 + s3);
    __syncthreads();
    if (t < 32) {
      float acc = 0.f;
#pragma unroll
      for (int i = 0; i < 8; i++) acc += part[i * 32 + t];
      xqh2[(size_t)b * PROJ_DIM + cc * 32 + t] = (_Float16)(2.0f * acc);
    }
  }
}

// ---------------------------------------------------------------------------
// gemm_score: round-0 structure with ONE change: BK 64 -> 128.
// 8 K-iterations instead of 16 -> 16 barrier drains instead of 32 (the
// barrier vmcnt/lgkm drain was the dominant per-iter overhead; MFMA count
// unchanged). LDS grows to 33.3 KB -> still 4 blocks/CU.
// Swizzle sw(c,r) = (c&8)|((c&7)^(r&7)) on 8-half chunks, applied on the
// READ path + inverse-swizzled global SOURCE for the B global_load_lds
// (linear LDS dest, per rule: both-sides-or-neither). sw is an involution.
// Grid 1024 flat: xcd=bid&7, idx=bid>>3, m-tile=xcd*32+(idx&31),
// n-tile=idx>>5 -> all 4 n-tiles of one m-tile on one XCD (A L2-resident).
// ---------------------------------------------------------------------------
__global__ __launch_bounds__(256) void gemm_score_kernel(
    const float* __restrict__ sx, const _Float16* __restrict__ W1,
    const _Float16* __restrict__ xqh2, float* __restrict__ scP) {
  __shared__ _Float16 At[32 * 128];  // A staging, chunk-swizzled (8 KB)
  __shared__ _Float16 Bt[64 * 128];  // B staging, linear dest (16 KB)
  __shared__ _Float16 Sx[32 * 72];   // sxp tile, padded stride 72
  __shared__ _Float16 Xl[32 * 64];   // 2*xq slice for this n-chunk

  const int tid = threadIdx.x;
  const int w = tid >> 6;
  const int lane = tid & 63;
  const int xcd = blockIdx.x & 7;
  const int idx = blockIdx.x >> 3;
  const int bm = (xcd * 32 + (idx & 31)) * 32;  // 0..255 m-tiles of 32 rows
  const int ntile = idx >> 5;                   // 0..3
  const int bn = ntile * 64;
  const int wm = w & 1, wn = w >> 1;
  const int m16 = lane & 15, quad = lane >> 4;

  // B gload lane mapping: instr i covers rows w*16+i*4 .. +3; lane ->
  // row sub = lane>>4, chunk c = lane&15; global chunk = sw(c, row).
  const int brsub = lane >> 4;  // 0..3
  const int bc = lane & 15;

  // load Xl: 32 b-rows x 64 halfs (this block's n-range)
  {
    const int r = tid >> 3, c = tid & 7;
    *(f16x8*)&Xl[r * 64 + c * 8] =
        *(const f16x8*)&xqh2[(size_t)r * PROJ_DIM + bn + c * 8];
  }

  // A staging: thread owns row = tid>>3 (0..31), chunks ac and ac+8.
  const int arow = tid >> 3;
  const int ac = tid & 7;
  const float* __restrict__ abase =
      sx + (size_t)(bm + arow) * FEAT_DIM + ac * 8;
  // sw(ac,arow)=ac^(arow&7); sw(ac+8,arow)=8|(ac^(arow&7)) -> +64 halfs
  _Float16* __restrict__ ad = &At[arow * 128 + (ac ^ (arow & 7)) * 8];

  f32x4 acc[2];
#pragma unroll
  for (int nt = 0; nt < 2; nt++) acc[nt] = (f32x4){0.f, 0.f, 0.f, 0.f};

  for (int kb = 0; kb < FEAT_DIM; kb += 128) {
    // stage A: 16 fp32 -> 16 fp16, two swizzled b128 LDS writes
    {
      const float4* gp0 = (const float4*)(abase + kb);
      const float4 v0 = gp0[0], v1 = gp0[1];
      const float4* gp1 = (const float4*)(abase + kb + 64);
      const float4 v2 = gp1[0], v3 = gp1[1];
      f16x8 h0 = {(_Float16)v0.x, (_Float16)v0.y, (_Float16)v0.z,
                  (_Float16)v0.w, (_Float16)v1.x, (_Float16)v1.y,
                  (_Float16)v1.z, (_Float16)v1.w};
      f16x8 h1 = {(_Float16)v2.x, (_Float16)v2.y, (_Float16)v2.z,
                  (_Float16)v2.w, (_Float16)v3.x, (_Float16)v3.y,
                  (_Float16)v3.z, (_Float16)v3.w};
      *(f16x8*)ad = h0;
      *(f16x8*)(ad + 64) = h1;
    }
    // stage B tile (64 n x 128 k fp16): 4 async instrs/wave, linear dest,
    // inverse-swizzled global source.
#pragma unroll
    for (int i = 0; i < 4; i++) {
      const int r = w * 16 + i * 4 + brsub;
      const int gc = (bc & 8) | ((bc & 7) ^ (r & 7));
      const _Float16* gp = W1 + (size_t)(bn + r) * FEAT_DIM + kb + gc * 8;
      __builtin_amdgcn_global_load_lds(
          (const __attribute__((address_space(1))) void*)gp,
          (__attribute__((address_space(3))) void*)(Bt +
                                                    (w * 16 + i * 4) * 128),
          16, 0, 0);
    }
    __syncthreads();

#pragma unroll
    for (int s = 0; s < 4; s++) {
      const int ch = s * 4 + quad;  // 0..15
      const int sw = ((ch & 8) | ((ch & 7) ^ (m16 & 7))) * 8;
      f16x8 af, bf[2];
      {
        const int row = wm * 16 + m16;
        af = *(f16x8*)&At[row * 128 + sw];
      }
#pragma unroll
      for (int nt = 0; nt < 2; nt++) {
        const int nrow = wn * 32 + nt * 16 + m16;
        bf[nt] = *(f16x8*)&Bt[nrow * 128 + sw];
      }
#pragma unroll
      for (int nt = 0; nt < 2; nt++)
        acc[nt] = __builtin_amdgcn_mfma_f32_16x16x32_f16(af, bf[nt], acc[nt],
                                                         0, 0, 0);
    }
    __syncthreads();
  }

  // ---- epilogue: sxp tile -> LDS (fp16, padded stride 72).
  // C/D layout: col = lane&15 (n), row = quad*4 + reg (m/j)
#pragma unroll
  for (int nt = 0; nt < 2; nt++)
#pragma unroll
    for (int r = 0; r < 4; r++) {
      const int jl = wm * 16 + quad * 4 + r;
      const int nl = wn * 32 + nt * 16 + m16;
      Sx[jl * 72 + nl] = (_Float16)acc[nt][r];
    }
  __syncthreads();

  // ---- fused partial score: thread t -> j = t&31, b-group = t>>5 (4 b's).
  // Half-wave shares b-group -> Xl reads are 2-address broadcasts (free).
  const int j = tid & 31;
  const int bg = tid >> 5;
  float dotb[4] = {0.f, 0.f, 0.f, 0.f};
  float rsq = 0.f;
#pragma unroll
  for (int c = 0; c < 8; c++) {
    const f16x8 hv = *(const f16x8*)&Sx[j * 72 + c * 8];
    const f16x2* hp = (const f16x2*)&hv;
#pragma unroll
    for (int i = 0; i < 4; i++)
      rsq = __builtin_amdgcn_fdot2(hp[i], hp[i], rsq, false);
#pragma unroll
    for (int b4 = 0; b4 < 4; b4++) {
      const f16x8 xv = *(const f16x8*)&Xl[(bg * 4 + b4) * 64 + c * 8];
      const f16x2* xp = (const f16x2*)&xv;
#pragma unroll
      for (int i = 0; i < 4; i++)
        dotb[b4] = __builtin_amdgcn_fdot2(hp[i], xp[i], dotb[b4], false);
    }
  }
  // write-once partial stores (no atomics, no zero-init)
  float* __restrict__ outP = scP + (size_t)ntile * BATCH * NUM_SUPPORT;
#pragma unroll
  for (int b4 = 0; b4 < 4; b4++) {
    outP[(size_t)(bg * 4 + b4) * NUM_SUPPORT + bm + j] = dotb[b4] - rsq;
  }
}

// ---------------------------------------------------------------------------
// finish: per batch row: sum 4 partials, row max, exp, class bins, log.
// One block (1024 thr) per b. (round-4 version, best measured: f32x4 loads,
// per-thread-contiguous 8-j layout, int4 label loads.)
// ---------------------------------------------------------------------------
__global__ __launch_bounds__(1024) void finish_kernel(
    const float* __restrict__ scP, const int* __restrict__ sy,
    float* __restrict__ out) {
  __shared__ float cls[N_CLASSES];
  __shared__ float redm[16];
  __shared__ float reds[16];

  const int b = blockIdx.x;
  const int t = threadIdx.x;
  const int lane = t & 63, wave = t >> 6;
  const size_t P = (size_t)BATCH * NUM_SUPPORT;
  const float* __restrict__ row0 =
      scP + (size_t)b * NUM_SUPPORT + (size_t)t * 8;

  // sum the 4 write-once partials with vector loads; track row max
  f32x4 sA, sB;
  {
    const f32x4 a0 = *(const f32x4*)(row0);
    const f32x4 a1 = *(const f32x4*)(row0 + P);
    const f32x4 a2 = *(const f32x4*)(row0 + 2 * P);
    const f32x4 a3 = *(const f32x4*)(row0 + 3 * P);
    sA = (a0 + a1) + (a2 + a3);
    const f32x4 b0 = *(const f32x4*)(row0 + 4);
    const f32x4 b1 = *(const f32x4*)(row0 + P + 4);
    const f32x4 b2 = *(const f32x4*)(row0 + 2 * P + 4);
    const f32x4 b3 = *(const f32x4*)(row0 + 3 * P + 4);
    sB = (b0 + b1) + (b2 + b3);
  }
  float m = -1e30f;
#pragma unroll
  for (int q = 0; q < 4; q++) m = fmaxf(m, fmaxf(sA[q], sB[q]));
#pragma unroll
  for (int o = 1; o < 64; o <<= 1) m = fmaxf(m, __shfl_xor(m, o, 64));
  if (lane == 0) redm[wave] = m;
  if (t < N_CLASSES) cls[t] = 0.0f;
  __syncthreads();
  float gm = redm[0];
#pragma unroll
  for (int i = 1; i < 16; i++) gm = fmaxf(gm, redm[i]);

  // exp + class binning (labels via two int4 loads)
  const int4 y0 = *(const int4*)(sy + t * 8);
  const int4 y1 = *(const int4*)(sy + t * 8 + 4);
  float lsum = 0.0f;
  {
    const float e0 = expf(sA[0] - gm);
    const float e1 = expf(sA[1] - gm);
    const float e2 = expf(sA[2] - gm);
    const float e3 = expf(sA[3] - gm);
    lsum += (e0 + e1) + (e2 + e3);
    atomicAdd(&cls[y0.x], e0);
    atomicAdd(&cls[y0.y], e1);
    atomicAdd(&cls[y0.z], e2);
    atomicAdd(&cls[y0.w], e3);
  }
  {
    const float e0 = expf(sB[0] - gm);
    const float e1 = expf(sB[1] - gm);
    const float e2 = expf(sB[2] - gm);
    const float e3 = expf(sB[3] - gm);
    lsum += (e0 + e1) + (e2 + e3);
    atomicAdd(&cls[y1.x], e0);
    atomicAdd(&cls[y1.y], e1);
    atomicAdd(&cls[y1.z], e2);
    atomicAdd(&cls[y1.w], e3);
  }
#pragma unroll
  for (int o = 1; o < 64; o <<= 1) lsum += __shfl_xor(lsum, o, 64);
  if (lane == 0) reds[wave] = lsum;
  __syncthreads();
  float total = 0.f;
#pragma unroll
  for (int i = 0; i < 16; i++) total += reds[i];
  const float inv = 1.0f / total;
  if (t < N_CLASSES) {
    out[(size_t)b * N_CLASSES + t] = logf(cls[t] * inv + 1e-12f);
  }
}

// ---------------------------------------------------------------------------
extern "C" void kernel_launch(void* const* d_in, const int* in_sizes, int n_in,
                              void* d_out, int out_size, void* d_ws,
                              size_t ws_size, hipStream_t stream) {
  const float* x = (const float*)d_in[0];   // (32, 1024)
  const float* sx = (const float*)d_in[1];  // (8192, 1024)
  const float* W = (const float*)d_in[2];   // (1024, 256)
  const int* sy = (const int*)d_in[3];      // (8192,)
  float* out = (float*)d_out;               // (32, 1000)

  char* p = (char*)d_ws;
  float* scP = (float*)p;         p += (size_t)4 * BATCH * NUM_SUPPORT * 4;
  _Float16* W1 = (_Float16*)p;    p += (size_t)PROJ_DIM * FEAT_DIM * 2;
  _Float16* xqh2 = (_Float16*)p;  // 32*256*2

  prelude_kernel<<<dim3(PW_BLOCKS + PX_BLOCKS), dim3(256), 0, stream>>>(
      W, x, W1, xqh2);
  gemm_score_kernel<<<dim3(1024), dim3(256), 0, stream>>>(sx, W1, xqh2, scP);
  finish_kernel<<<dim3(BATCH), dim3(1024), 0, stream>>>(scP, sy, out);
}